// Round 8
// baseline (356.995 us; speedup 1.0000x reference)
//
#include <hip/hip_runtime.h>

typedef _Float16 half8 __attribute__((ext_vector_type(8)));
typedef float f32x4 __attribute__((ext_vector_type(4)));

#define SEQ   4096
#define DIN   512
#define HID   1024
#define KMEM  256
#define NB    8
#define KC    768        // KMEM + DIN
#define VP    4352       // padded length of each phase copy of reversed u
#define OUT_H_ELEMS 33554432ull   // 8*4096*1024

__device__ __forceinline__ void load_lds16(const void* g, void* l) {
  __builtin_amdgcn_global_load_lds(
      (const __attribute__((address_space(1))) unsigned int*)g,
      (__attribute__((address_space(3))) unsigned int*)l, 16, 0, 0);
}

// ---------------- u = relu(x . W_u + b); emit xh (fp16) and v2 ----------------
// (unchanged)
__global__ __launch_bounds__(256) void u_kernel(
    const float* __restrict__ x, const float* __restrict__ Wu,
    const float* __restrict__ Wub,
    const float* __restrict__ Hf, const float* __restrict__ Wf,
    _Float16* __restrict__ xh, _Float16* __restrict__ v2,
    _Float16* __restrict__ Hh, _Float16* __restrict__ Wh)
{
  int tid_g = blockIdx.x * 256 + threadIdx.x;      // 0..2097151
  if (tid_g < KMEM * SEQ) Hh[tid_g] = (_Float16)Hf[tid_g];
  if (tid_g < HID * KC)   Wh[tid_g] = (_Float16)Wf[tid_g];
  if (tid_g < NB * 8 * 256) {                      // v2 pad zero
    int b2 = tid_g >> 11, rem = tid_g & 2047, p = rem >> 8, z = rem & 255;
    int t = (z < p) ? z : 4096 + z;                // [0,p) U [4096+p, 4352)
    v2[((size_t)b2 * 8 + p) * VP + t] = (_Float16)0.f;
  }

  int w = threadIdx.x >> 6, lane = threadIdx.x & 63;
  int row = blockIdx.x * 4 + w;               // 0..32767  (= b*4096 + s)
  const float4* xr = (const float4*)(x + (size_t)row * DIN);
  const float4* wr = (const float4*)Wu;
  float4 a0 = xr[lane * 2], a1 = xr[lane * 2 + 1];
  float4 w0 = wr[lane * 2], w1 = wr[lane * 2 + 1];
  float dot = a0.x * w0.x + a0.y * w0.y + a0.z * w0.z + a0.w * w0.w
            + a1.x * w1.x + a1.y * w1.y + a1.z * w1.z + a1.w * w1.w;
  half8 hv;
  hv[0] = (_Float16)a0.x; hv[1] = (_Float16)a0.y;
  hv[2] = (_Float16)a0.z; hv[3] = (_Float16)a0.w;
  hv[4] = (_Float16)a1.x; hv[5] = (_Float16)a1.y;
  hv[6] = (_Float16)a1.z; hv[7] = (_Float16)a1.w;
  *((half8*)(xh + (size_t)row * DIN + lane * 8)) = hv;
  #pragma unroll
  for (int off = 32; off > 0; off >>= 1) dot += __shfl_xor(dot, off);
  float u = dot + Wub[0];
  u = u > 0.f ? u : 0.f;
  if (lane < 8) {
    int s = row & (SEQ - 1), b = row >> 12;
    v2[(size_t)b * 8 * VP + (size_t)lane * VP + (4095 - s + lane)] = (_Float16)u;
  }
}

// ---------------- conv: m[b,s,k] = sum_{r=0..s} u[b,s-r] * H[k,r] ----------------
// (unchanged from round 2 — it won; its B layout is already conflict-free)
__global__ __launch_bounds__(256, 3) void conv_kernel(
    const _Float16* __restrict__ Hh, const _Float16* __restrict__ v2,
    _Float16* __restrict__ mh)
{
  __shared__ _Float16 Bs[2][128 * 64];  // [col][r-chunk 64], swizzled slots
  __shared__ _Float16 Aw[2][8 * 208];   // 8 phase copies of the u-window
  int g = blockIdx.x;                   // 0..511
  int cb = g & 15;
  int b = cb >> 1, kt = cb & 1;
  int jj = g >> 4;                      // 0..31
  int its = (jj < 16) ? jj : (47 - jj); // complement pairing: g vs g+256
  int s0 = its * 128, k0 = kt * 128;
  int tid = threadIdx.x;
  int w = tid >> 6, lane = tid & 63;
  int wr = w >> 1, wc = w & 1;
  int lm = lane & 15, q = lane >> 4;
  const _Float16* v2b = v2 + (size_t)b * 8 * VP;
  int gb = 3968 - s0;                   // window start at r0=0 (>=0, 8-aligned)

  int aoffs[4];
  #pragma unroll
  for (int mi = 0; mi < 4; mi++) {
    int X = wr * 64 + mi * 16 + lm;     // s-offset within tile (0..127)
    int p = (X + 1) & 7;
    aoffs[mi] = p * 208 + (127 - X + p) + q * 8;
  }
  int boffs[4];
  #pragma unroll
  for (int ni = 0; ni < 4; ni++) {
    int col = wc * 64 + ni * 16 + lm;
    boffs[ni] = col * 64 + ((q ^ (lm & 7)) << 3);
  }

  int ap = tid / 26, aidx = tid - ap * 26;   // A staging map (208 x 16B chunks)

  f32x4 acc[4][4] = {};
  int iters = 2 * (its + 1);            // K64 chunks to cover r in [0, s0+128)

  // preload iter 0 into buf 0
  {
    if (tid < 208)
      load_lds16(v2b + (size_t)ap * VP + gb + aidx * 8, Aw[0] + tid * 8);
    #pragma unroll
    for (int p2 = 0; p2 < 4; p2++) {
      int c = p2 * 256 + tid;
      int col = c >> 3, sl = c & 7;
      load_lds16(Hh + (size_t)(k0 + col) * SEQ + ((sl ^ (col & 7)) << 3),
                 Bs[0] + (size_t)c * 8);
    }
  }

  for (int it = 0; it < iters; ++it) {
    int buf = it & 1;
    __syncthreads();                    // vmcnt(0): buf's loads landed
    if (it + 1 < iters) {               // prefetch next K64 chunk into buf^1
      int r0 = (it + 1) * 64;
      if (tid < 208)
        load_lds16(v2b + (size_t)ap * VP + gb + r0 + aidx * 8, Aw[buf ^ 1] + tid * 8);
      #pragma unroll
      for (int p2 = 0; p2 < 4; p2++) {
        int c = p2 * 256 + tid;
        int col = c >> 3, sl = c & 7;
        load_lds16(Hh + (size_t)(k0 + col) * SEQ + r0 + ((sl ^ (col & 7)) << 3),
                   Bs[buf ^ 1] + (size_t)c * 8);
      }
    }
    #pragma unroll
    for (int kq = 0; kq < 2; kq++) {
      half8 af[4], bf[4];
      #pragma unroll
      for (int mi = 0; mi < 4; mi++)
        af[mi] = *((const half8*)(Aw[buf] + aoffs[mi] + kq * 32));
      #pragma unroll
      for (int ni = 0; ni < 4; ni++)
        bf[ni] = *((const half8*)(Bs[buf] + (boffs[ni] ^ (kq << 5))));
      #pragma unroll
      for (int mi = 0; mi < 4; mi++)
        #pragma unroll
        for (int ni = 0; ni < 4; ni++)
          acc[mi][ni] = __builtin_amdgcn_mfma_f32_16x16x32_f16(af[mi], bf[ni], acc[mi][ni], 0, 0, 0);
    }
  }
  size_t rowbase = (size_t)b * SEQ;
  #pragma unroll
  for (int mi = 0; mi < 4; mi++) {
    #pragma unroll
    for (int ni = 0; ni < 4; ni++) {
      int kout = k0 + wc * 64 + ni * 16 + lm;
      #pragma unroll
      for (int r = 0; r < 4; r++) {
        int sout = s0 + wr * 64 + mi * 16 + q * 4 + r;
        mh[(rowbase + sout) * KMEM + kout] = (_Float16)acc[mi][ni][r];
      }
    }
  }
}

// ---------------- h = relu([m, x] . W_h^T + b); also h[:, -1, :] tail ----------------
// R6 structure (best measured h: 128x256 tile, 512 thr, 8 waves of 64x64,
// 2-buf __syncthreads, A+B LDS via global_load_lds) with ONE change:
// slot-major LDS layout  A[4 slots][128 rows][16B], B[4][256][16B].
// Frag-read bank = row*4 mod 32 -> 2 lanes/bank (free, m136). This kills the
// 6.29M SQ_LDS_BANK_CONFLICT that R7 proved real (R7's A layout measured 0).
// Staging dest stays linear (chunk c*16, rule #21); source re-indexed to
// (row=c&127|c&255, slot=c>>7|c>>8). Same K order -> bit-identical output.
// B-direct-from-L2 (R7) reverted: it serialized MFMA behind L2 latency.
__global__ __launch_bounds__(512, 4) void h_kernel(
    const _Float16* __restrict__ mh, const _Float16* __restrict__ xh,
    const _Float16* __restrict__ Wh, const float* __restrict__ Whb,
    float* __restrict__ out)
{
  __shared__ _Float16 As[2][4 * 128 * 8];   // [slot][row][8 halfs] = 4096 h
  __shared__ _Float16 Bs[2][4 * 256 * 8];   // [slot][row][8 halfs] = 8192 h
  int id = blockIdx.x;                    // 0..1023; HW round-robins id%8 -> XCD
  int wgid = (id & 7) * 128 + (id >> 3);  // bijective (1024 = 8*128)
  int mt = wgid >> 2;                     // 0..255
  int nt = wgid & 3;                      // 0..3
  int tid = threadIdx.x, w = tid >> 6, lane = tid & 63;
  int wr = w >> 2, wc = w & 3;            // 2(M) x 4(N) waves, 64x64 each
  int lm = lane & 15, q = lane >> 4;

  // A staging: 512 chunks (c = tid): slot = c>>7, row = c&127
  int offM, offX;
  {
    int rowA = tid & 127, slA = tid >> 7;
    offM = (mt * 128 + rowA) * KMEM + slA * 8;
    offX = (mt * 128 + rowA) * DIN  + slA * 8;
  }
  // B staging: 1024 chunks (c = r*512+tid): slot = c>>8, row = c&255
  int offB[2];
  #pragma unroll
  for (int r = 0; r < 2; ++r) {
    int c = r * 512 + tid;
    int rowB = c & 255, slB = c >> 8;
    offB[r] = (nt * 256 + rowB) * KC + slB * 8;
  }

  // frag-read offsets (slot-major): A: q*1024 + X*8 ; B: q*2048 + Y*8
  int aoff[4], boff[4];
  #pragma unroll
  for (int mi = 0; mi < 4; ++mi)
    aoff[mi] = q * 1024 + (wr * 64 + mi * 16 + lm) * 8;
  #pragma unroll
  for (int ni = 0; ni < 4; ++ni)
    boff[ni] = q * 2048 + (wc * 64 + ni * 16 + lm) * 8;

  f32x4 acc[4][4] = {};
  // preload tile 0 into buf 0 (kk=0 < KMEM -> A from mh)
  {
    load_lds16(mh + offM, As[0] + tid * 8);
    #pragma unroll
    for (int r = 0; r < 2; ++r)
      load_lds16(Wh + offB[r], Bs[0] + (size_t)(r * 512 + tid) * 8);
  }

  for (int it = 0; it < 24; ++it) {
    int buf = it & 1;
    __syncthreads();                    // buf's loads landed; buf^1 reads done
    if (it + 1 < 24) {
      int kk = (it + 1) * 32;
      const _Float16* srcA = (kk < KMEM) ? (mh + offM + kk)
                                         : (xh + offX + (kk - KMEM));
      load_lds16(srcA, As[buf ^ 1] + tid * 8);
      #pragma unroll
      for (int r = 0; r < 2; ++r)
        load_lds16(Wh + offB[r] + kk, Bs[buf ^ 1] + (size_t)(r * 512 + tid) * 8);
    }
    half8 af[4], bf[4];
    #pragma unroll
    for (int mi = 0; mi < 4; ++mi) af[mi] = *((const half8*)(As[buf] + aoff[mi]));
    #pragma unroll
    for (int ni = 0; ni < 4; ++ni) bf[ni] = *((const half8*)(Bs[buf] + boff[ni]));
    __builtin_amdgcn_s_setprio(1);
    #pragma unroll
    for (int mi = 0; mi < 4; ++mi)
      #pragma unroll
      for (int ni = 0; ni < 4; ++ni)
        acc[mi][ni] = __builtin_amdgcn_mfma_f32_16x16x32_f16(af[mi], bf[ni], acc[mi][ni], 0, 0, 0);
    __builtin_amdgcn_s_setprio(0);
  }

  // epilogue: bias + relu + nontemporal store fp32 (+ last-timestep tail)
  #pragma unroll
  for (int ni = 0; ni < 4; ni++) {
    int colg = nt * 256 + wc * 64 + ni * 16 + lm;
    float bias = Whb[colg];
    #pragma unroll
    for (int mi = 0; mi < 4; mi++) {
      #pragma unroll
      for (int r = 0; r < 4; r++) {
        int rowg = mt * 128 + wr * 64 + mi * 16 + q * 4 + r;
        float v = acc[mi][ni][r] + bias;
        v = v > 0.f ? v : 0.f;
        __builtin_nontemporal_store(v, &out[(size_t)rowg * HID + colg]);
        if ((rowg & (SEQ - 1)) == SEQ - 1)
          __builtin_nontemporal_store(
              v, &out[OUT_H_ELEMS + (size_t)(rowg >> 12) * HID + colg]);
      }
    }
  }
}

extern "C" void kernel_launch(void* const* d_in, const int* in_sizes, int n_in,
                              void* d_out, int out_size, void* d_ws, size_t ws_size,
                              hipStream_t stream) {
  const float* x   = (const float*)d_in[0];   // (8, 4096, 512)
  const float* Wu  = (const float*)d_in[1];   // (1, 512)
  const float* Wub = (const float*)d_in[2];   // (1,)
  const float* Whw = (const float*)d_in[3];   // (1024, 768)
  const float* Whb = (const float*)d_in[4];   // (1024,)
  const float* Hf  = (const float*)d_in[5];   // (256, 4096)
  float* out = (float*)d_out;

  char* ws = (char*)d_ws;
  _Float16* Hh = (_Float16*)(ws);                         // 2,097,152 B
  _Float16* Wh = (_Float16*)(ws + 2097152);               // 1,572,864 B
  _Float16* v2 = (_Float16*)(ws + 3670016);               //   557,056 B
  _Float16* xh = (_Float16*)(ws + 4227072);               // 33,554,432 B
  _Float16* mh = (_Float16*)(ws + 37781504);              // 16,777,216 B  (end 54,558,720)

  u_kernel<<<dim3(8192), dim3(256), 0, stream>>>(x, Wu, Wub, Hf, Whw, xh, v2, Hh, Wh);
  conv_kernel<<<dim3(512), dim3(256), 0, stream>>>(Hh, v2, mh);
  h_kernel<<<dim3(1024), dim3(512), 0, stream>>>(mh, xh, Wh, Whb, out);
}

// Round 9
// 304.336 us; speedup vs baseline: 1.1730x; 1.1730x over previous
//
#include <hip/hip_runtime.h>

typedef _Float16 half8 __attribute__((ext_vector_type(8)));
typedef float f32x4 __attribute__((ext_vector_type(4)));

#define SEQ   4096
#define DIN   512
#define HID   1024
#define KMEM  256
#define NB    8
#define KC    768        // KMEM + DIN
#define VP    4352       // padded length of each phase copy of reversed u
#define OUT_H_ELEMS 33554432ull   // 8*4096*1024

__device__ __forceinline__ void load_lds16(const void* g, void* l) {
  __builtin_amdgcn_global_load_lds(
      (const __attribute__((address_space(1))) unsigned int*)g,
      (__attribute__((address_space(3))) unsigned int*)l, 16, 0, 0);
}

// ---------------- u = relu(x . W_u + b); emit xh (fp16) and v2 ----------------
// (unchanged)
__global__ __launch_bounds__(256) void u_kernel(
    const float* __restrict__ x, const float* __restrict__ Wu,
    const float* __restrict__ Wub,
    const float* __restrict__ Hf, const float* __restrict__ Wf,
    _Float16* __restrict__ xh, _Float16* __restrict__ v2,
    _Float16* __restrict__ Hh, _Float16* __restrict__ Wh)
{
  int tid_g = blockIdx.x * 256 + threadIdx.x;      // 0..2097151
  if (tid_g < KMEM * SEQ) Hh[tid_g] = (_Float16)Hf[tid_g];
  if (tid_g < HID * KC)   Wh[tid_g] = (_Float16)Wf[tid_g];
  if (tid_g < NB * 8 * 256) {                      // v2 pad zero
    int b2 = tid_g >> 11, rem = tid_g & 2047, p = rem >> 8, z = rem & 255;
    int t = (z < p) ? z : 4096 + z;                // [0,p) U [4096+p, 4352)
    v2[((size_t)b2 * 8 + p) * VP + t] = (_Float16)0.f;
  }

  int w = threadIdx.x >> 6, lane = threadIdx.x & 63;
  int row = blockIdx.x * 4 + w;               // 0..32767  (= b*4096 + s)
  const float4* xr = (const float4*)(x + (size_t)row * DIN);
  const float4* wr = (const float4*)Wu;
  float4 a0 = xr[lane * 2], a1 = xr[lane * 2 + 1];
  float4 w0 = wr[lane * 2], w1 = wr[lane * 2 + 1];
  float dot = a0.x * w0.x + a0.y * w0.y + a0.z * w0.z + a0.w * w0.w
            + a1.x * w1.x + a1.y * w1.y + a1.z * w1.z + a1.w * w1.w;
  half8 hv;
  hv[0] = (_Float16)a0.x; hv[1] = (_Float16)a0.y;
  hv[2] = (_Float16)a0.z; hv[3] = (_Float16)a0.w;
  hv[4] = (_Float16)a1.x; hv[5] = (_Float16)a1.y;
  hv[6] = (_Float16)a1.z; hv[7] = (_Float16)a1.w;
  *((half8*)(xh + (size_t)row * DIN + lane * 8)) = hv;
  #pragma unroll
  for (int off = 32; off > 0; off >>= 1) dot += __shfl_xor(dot, off);
  float u = dot + Wub[0];
  u = u > 0.f ? u : 0.f;
  if (lane < 8) {
    int s = row & (SEQ - 1), b = row >> 12;
    v2[(size_t)b * 8 * VP + (size_t)lane * VP + (4095 - s + lane)] = (_Float16)u;
  }
}

// ---------------- conv: m[b,s,k] = sum_{r=0..s} u[b,s-r] * H[k,r] ----------------
// (unchanged from round 2 — it won)
__global__ __launch_bounds__(256, 3) void conv_kernel(
    const _Float16* __restrict__ Hh, const _Float16* __restrict__ v2,
    _Float16* __restrict__ mh)
{
  __shared__ _Float16 Bs[2][128 * 64];  // [col][r-chunk 64], swizzled slots
  __shared__ _Float16 Aw[2][8 * 208];   // 8 phase copies of the u-window
  int g = blockIdx.x;                   // 0..511
  int cb = g & 15;
  int b = cb >> 1, kt = cb & 1;
  int jj = g >> 4;                      // 0..31
  int its = (jj < 16) ? jj : (47 - jj); // complement pairing: g vs g+256
  int s0 = its * 128, k0 = kt * 128;
  int tid = threadIdx.x;
  int w = tid >> 6, lane = tid & 63;
  int wr = w >> 1, wc = w & 1;
  int lm = lane & 15, q = lane >> 4;
  const _Float16* v2b = v2 + (size_t)b * 8 * VP;
  int gb = 3968 - s0;                   // window start at r0=0 (>=0, 8-aligned)

  int aoffs[4];
  #pragma unroll
  for (int mi = 0; mi < 4; mi++) {
    int X = wr * 64 + mi * 16 + lm;     // s-offset within tile (0..127)
    int p = (X + 1) & 7;
    aoffs[mi] = p * 208 + (127 - X + p) + q * 8;
  }
  int boffs[4];
  #pragma unroll
  for (int ni = 0; ni < 4; ni++) {
    int col = wc * 64 + ni * 16 + lm;
    boffs[ni] = col * 64 + ((q ^ (lm & 7)) << 3);
  }

  int ap = tid / 26, aidx = tid - ap * 26;   // A staging map (208 x 16B chunks)

  f32x4 acc[4][4] = {};
  int iters = 2 * (its + 1);            // K64 chunks to cover r in [0, s0+128)

  // preload iter 0 into buf 0
  {
    if (tid < 208)
      load_lds16(v2b + (size_t)ap * VP + gb + aidx * 8, Aw[0] + tid * 8);
    #pragma unroll
    for (int p2 = 0; p2 < 4; p2++) {
      int c = p2 * 256 + tid;
      int col = c >> 3, sl = c & 7;
      load_lds16(Hh + (size_t)(k0 + col) * SEQ + ((sl ^ (col & 7)) << 3),
                 Bs[0] + (size_t)c * 8);
    }
  }

  for (int it = 0; it < iters; ++it) {
    int buf = it & 1;
    __syncthreads();                    // vmcnt(0): buf's loads landed
    if (it + 1 < iters) {               // prefetch next K64 chunk into buf^1
      int r0 = (it + 1) * 64;
      if (tid < 208)
        load_lds16(v2b + (size_t)ap * VP + gb + r0 + aidx * 8, Aw[buf ^ 1] + tid * 8);
      #pragma unroll
      for (int p2 = 0; p2 < 4; p2++) {
        int c = p2 * 256 + tid;
        int col = c >> 3, sl = c & 7;
        load_lds16(Hh + (size_t)(k0 + col) * SEQ + r0 + ((sl ^ (col & 7)) << 3),
                   Bs[buf ^ 1] + (size_t)c * 8);
      }
    }
    #pragma unroll
    for (int kq = 0; kq < 2; kq++) {
      half8 af[4], bf[4];
      #pragma unroll
      for (int mi = 0; mi < 4; mi++)
        af[mi] = *((const half8*)(Aw[buf] + aoffs[mi] + kq * 32));
      #pragma unroll
      for (int ni = 0; ni < 4; ni++)
        bf[ni] = *((const half8*)(Bs[buf] + (boffs[ni] ^ (kq << 5))));
      #pragma unroll
      for (int mi = 0; mi < 4; mi++)
        #pragma unroll
        for (int ni = 0; ni < 4; ni++)
          acc[mi][ni] = __builtin_amdgcn_mfma_f32_16x16x32_f16(af[mi], bf[ni], acc[mi][ni], 0, 0, 0);
    }
  }
  size_t rowbase = (size_t)b * SEQ;
  #pragma unroll
  for (int mi = 0; mi < 4; mi++) {
    #pragma unroll
    for (int ni = 0; ni < 4; ni++) {
      int kout = k0 + wc * 64 + ni * 16 + lm;
      #pragma unroll
      for (int r = 0; r < 4; r++) {
        int sout = s0 + wr * 64 + mi * 16 + q * 4 + r;
        mh[(rowbase + sout) * KMEM + kout] = (_Float16)acc[mi][ni][r];
      }
    }
  }
}

// ---------------- h = relu([m, x] . W_h^T + b); also h[:, -1, :] tail ----------------
// R6 structure verbatim (best h measured: 128x256, 512 thr, 8 waves of 64x64,
// 2-buf __syncthreads, A+B staged via global_load_lds, 64-B-segment coalesced
// staging). ONE change: the slot-XOR is now (row>>1)&3 (was (row>>2)&3).
// Derivation: 64-B rows wrap the 32 banks every 2 rows, so lanes lm,lm+2
// collide unless the slot differs between rows 2 apart -> f(row)=(row>>1)&3.
// Result: exactly 2 lanes/bank (lm,lm+8) = free (m136). R5/R6's (row>>2)
// version provably left the 6.29M conflicts unchanged; R8 proved slot-major
// kills conflicts but wrecks staging coalescing. This keeps both properties.
// Read-side slot collapses to q ^ ((lm>>1)&3) (frag rows = 16k + lm).
// Pure permutation, K order unchanged -> bit-identical output.
__global__ __launch_bounds__(512, 4) void h_kernel(
    const _Float16* __restrict__ mh, const _Float16* __restrict__ xh,
    const _Float16* __restrict__ Wh, const float* __restrict__ Whb,
    float* __restrict__ out)
{
  __shared__ _Float16 As[2][128 * 32];
  __shared__ _Float16 Bs[2][256 * 32];
  int id = blockIdx.x;                    // 0..1023; HW round-robins id%8 -> XCD
  int wgid = (id & 7) * 128 + (id >> 3);  // bijective (1024 = 8*128)
  int mt = wgid >> 2;                     // 0..255
  int nt = wgid & 3;                      // 0..3
  int tid = threadIdx.x, w = tid >> 6, lane = tid & 63;
  int wr = w >> 2, wc = w & 3;            // 2(M) x 4(N) waves, 64x64 each
  int lm = lane & 15, q = lane >> 4;

  // staging maps (slot-XOR swizzled source, linear LDS dest; 64-B segments)
  int offM, offX;
  {
    int rowA = tid >> 2, chA = tid & 3;
    int swA = chA ^ ((rowA >> 1) & 3);
    offM = (mt * 128 + rowA) * KMEM + swA * 8;
    offX = (mt * 128 + rowA) * DIN  + swA * 8;
  }
  int offB[2];
  #pragma unroll
  for (int r = 0; r < 2; ++r) {
    int c = r * 512 + tid;
    int rowB = c >> 2, chB = c & 3;
    int swB = chB ^ ((rowB >> 1) & 3);
    offB[r] = (nt * 256 + rowB) * KC + swB * 8;
  }

  // frag-read offsets (swizzled slot collapses to per-lane constant)
  int qs = (q ^ ((lm >> 1) & 3)) << 3;
  int aoff[4], boff[4];
  #pragma unroll
  for (int mi = 0; mi < 4; ++mi) aoff[mi] = (wr * 64 + mi * 16 + lm) * 32 + qs;
  #pragma unroll
  for (int ni = 0; ni < 4; ++ni) boff[ni] = (wc * 64 + ni * 16 + lm) * 32 + qs;

  f32x4 acc[4][4] = {};
  // preload tile 0 into buf 0 (kk=0 < KMEM -> A from mh)
  {
    load_lds16(mh + offM, As[0] + tid * 8);
    #pragma unroll
    for (int r = 0; r < 2; ++r)
      load_lds16(Wh + offB[r], Bs[0] + (size_t)(r * 512 + tid) * 8);
  }

  for (int it = 0; it < 24; ++it) {
    int buf = it & 1;
    __syncthreads();                    // buf's loads landed; buf^1 reads done
    if (it + 1 < 24) {
      int kk = (it + 1) * 32;
      const _Float16* srcA = (kk < KMEM) ? (mh + offM + kk)
                                         : (xh + offX + (kk - KMEM));
      load_lds16(srcA, As[buf ^ 1] + tid * 8);
      #pragma unroll
      for (int r = 0; r < 2; ++r)
        load_lds16(Wh + offB[r] + kk, Bs[buf ^ 1] + (size_t)(r * 512 + tid) * 8);
    }
    half8 af[4], bf[4];
    #pragma unroll
    for (int mi = 0; mi < 4; ++mi) af[mi] = *((const half8*)(As[buf] + aoff[mi]));
    #pragma unroll
    for (int ni = 0; ni < 4; ++ni) bf[ni] = *((const half8*)(Bs[buf] + boff[ni]));
    __builtin_amdgcn_s_setprio(1);
    #pragma unroll
    for (int mi = 0; mi < 4; ++mi)
      #pragma unroll
      for (int ni = 0; ni < 4; ++ni)
        acc[mi][ni] = __builtin_amdgcn_mfma_f32_16x16x32_f16(af[mi], bf[ni], acc[mi][ni], 0, 0, 0);
    __builtin_amdgcn_s_setprio(0);
  }

  // epilogue: bias + relu + nontemporal store fp32 (+ last-timestep tail)
  #pragma unroll
  for (int ni = 0; ni < 4; ni++) {
    int colg = nt * 256 + wc * 64 + ni * 16 + lm;
    float bias = Whb[colg];
    #pragma unroll
    for (int mi = 0; mi < 4; mi++) {
      #pragma unroll
      for (int r = 0; r < 4; r++) {
        int rowg = mt * 128 + wr * 64 + mi * 16 + q * 4 + r;
        float v = acc[mi][ni][r] + bias;
        v = v > 0.f ? v : 0.f;
        __builtin_nontemporal_store(v, &out[(size_t)rowg * HID + colg]);
        if ((rowg & (SEQ - 1)) == SEQ - 1)
          __builtin_nontemporal_store(
              v, &out[OUT_H_ELEMS + (size_t)(rowg >> 12) * HID + colg]);
      }
    }
  }
}

extern "C" void kernel_launch(void* const* d_in, const int* in_sizes, int n_in,
                              void* d_out, int out_size, void* d_ws, size_t ws_size,
                              hipStream_t stream) {
  const float* x   = (const float*)d_in[0];   // (8, 4096, 512)
  const float* Wu  = (const float*)d_in[1];   // (1, 512)
  const float* Wub = (const float*)d_in[2];   // (1,)
  const float* Whw = (const float*)d_in[3];   // (1024, 768)
  const float* Whb = (const float*)d_in[4];   // (1024,)
  const float* Hf  = (const float*)d_in[5];   // (256, 4096)
  float* out = (float*)d_out;

  char* ws = (char*)d_ws;
  _Float16* Hh = (_Float16*)(ws);                         // 2,097,152 B
  _Float16* Wh = (_Float16*)(ws + 2097152);               // 1,572,864 B
  _Float16* v2 = (_Float16*)(ws + 3670016);               //   557,056 B
  _Float16* xh = (_Float16*)(ws + 4227072);               // 33,554,432 B
  _Float16* mh = (_Float16*)(ws + 37781504);              // 16,777,216 B  (end 54,558,720)

  u_kernel<<<dim3(8192), dim3(256), 0, stream>>>(x, Wu, Wub, Hf, Whw, xh, v2, Hh, Wh);
  conv_kernel<<<dim3(512), dim3(256), 0, stream>>>(Hh, v2, mh);
  h_kernel<<<dim3(1024), dim3(512), 0, stream>>>(mh, xh, Wh, Whb, out);
}